// Round 8
// baseline (745.787 us; speedup 1.0000x reference)
//
#include <hip/hip_runtime.h>
#include <hip/hip_bf16.h>

#define VOCAB 32000
#define DIM   128
#define BATCH 1024
#define CTX   10
#define SHIFT 20.0f
#define NSLICE 8
#define ROWS_PER_SLICE 128         // batch rows per slice (BATCH/NSLICE)
#define SCAN_ITEMS (BATCH * 5)     // 5120 items, each = 2 ctx rows (256 KB)
#define GEMM_X (VOCAB / 64)        // 500 col-tiles per slice
#define MEGA_BLOCKS 512

typedef __bf16 bf16x8 __attribute__((ext_vector_type(8)));
typedef float  f32x4  __attribute__((ext_vector_type(4)));
typedef unsigned uintx4 __attribute__((ext_vector_type(4)));

static __device__ __forceinline__ unsigned short bf16_hi(float x) {
    __hip_bfloat16 h = __float2bfloat16(x);
    return __builtin_bit_cast(unsigned short, h);
}
static __device__ __forceinline__ float bf16_back(unsigned short u) {
    __hip_bfloat16 h = __builtin_bit_cast(__hip_bfloat16, u);
    return __bfloat162float(h);
}

union u4s8 { uint4 v; unsigned short s[8]; unsigned long long q[2]; };

struct Ctl {
    unsigned scan_ticket;
    unsigned gemm_ticket[NSLICE];
    unsigned slice_cnt[NSLICE];
    unsigned row_cnt[BATCH];
    int      idx[BATCH * CTX];
    float    psum[BATCH];
};

// relaxed agent-scope atomic helpers (coherent-point ops; no L2 wb needed)
static __device__ __forceinline__ unsigned aadd(unsigned* p, unsigned v) {
    return __hip_atomic_fetch_add(p, v, __ATOMIC_RELAXED, __HIP_MEMORY_SCOPE_AGENT);
}
static __device__ __forceinline__ unsigned aldu(unsigned* p) {
    return __hip_atomic_load(p, __ATOMIC_RELAXED, __HIP_MEMORY_SCOPE_AGENT);
}
static __device__ __forceinline__ int aldi(int* p) {
    return __hip_atomic_load(p, __ATOMIC_RELAXED, __HIP_MEMORY_SCOPE_AGENT);
}
static __device__ __forceinline__ void asti(int* p, int v) {
    __hip_atomic_store(p, v, __ATOMIC_RELAXED, __HIP_MEMORY_SCOPE_AGENT);
}
static __device__ __forceinline__ void astq(unsigned long long* p, unsigned long long v) {
    __hip_atomic_store(p, v, __ATOMIC_RELAXED, __HIP_MEMORY_SCOPE_AGENT);
}

// ---------------------------------------------------------------------------
// init: reset control block each call (harness does not re-poison between
// replays; determinism requires we re-init ourselves).
// ---------------------------------------------------------------------------
__global__ __launch_bounds__(256) void init_kernel(Ctl* c) {
    const int t = blockIdx.x * 256 + threadIdx.x;
    if (t == 0) c->scan_ticket = 0;
    if (t < NSLICE) { c->gemm_ticket[t] = 0; c->slice_cnt[t] = 0; }
    if (t < BATCH)  { c->row_cnt[t] = 0; c->psum[t] = 0.f; }
    for (int k = t; k < BATCH * CTX; k += gridDim.x * 256) c->idx[k] = -1;
}

// ---------------------------------------------------------------------------
// convert_w: bf16 hi/lo split of w, transposed + fragment-swizzled (r7 form).
// Separate kernel so its plain stores are boundary-flushed before mega reads.
// ---------------------------------------------------------------------------
__global__ __launch_bounds__(256) void convert_w_kernel(
    const float* __restrict__ w, uint4* __restrict__ wsh, uint4* __restrict__ wsl) {
    const int n   = blockIdx.x * 256 + threadIdx.x;
    const int k0i = blockIdx.y;
    const int base = (n >> 4) * 256 + k0i * 64 + (n & 15);
#pragma unroll
    for (int kg = 0; kg < 4; ++kg) {
        u4s8 vh, vl;
#pragma unroll
        for (int j = 0; j < 8; ++j) {
            float x = w[(k0i * 32 + kg * 8 + j) * VOCAB + n];
            unsigned short hh = bf16_hi(x);
            vh.s[j] = hh;
            vl.s[j] = bf16_hi(x - bf16_back(hh));
        }
        wsh[base + kg * 16] = vh.v;
        wsl[base + kg * 16] = vl.v;
    }
}

// ---------------------------------------------------------------------------
// megakernel: persistent work-stealing pipeline.
//   scan item (2 ctx rows): stream 256KB, atomic-store idx; last item of a
//     batch row computes avg+bf16-split-pack (atomic u64 stores to LLC),
//     bumps slice counter.
//   gemm tile (slice s, x): r7's validated MFMA tile (BM=128/BN=64), exp
//     epilogue + atomic psum.
// 1/4 of blocks prefer gemm, 3/4 prefer scan; everyone steals the other kind
// when their preference is empty -> deadlock-free, both pipes busy.
// ---------------------------------------------------------------------------
__global__ __launch_bounds__(256) void mega_kernel(
    const float* __restrict__ batch, const float* __restrict__ emb,
    uint4* __restrict__ ash, uint4* __restrict__ asl,
    const uint4* __restrict__ wsh, const uint4* __restrict__ wsl,
    float* __restrict__ out, Ctl* __restrict__ ctl) {
    const int tid = threadIdx.x;

    __shared__ int s_kind;
    __shared__ unsigned s_p0, s_p1;
    __shared__ int s_flag;
    __shared__ int s_idx[CTX];
    __shared__ unsigned short s_h[DIM], s_l[DIM];

    // tid0-private scheduler state (bitmask, not bool[] -> stays in SGPRs)
    unsigned drmask = 0;
    bool scan_done = false;
    const bool prefer_gemm = ((blockIdx.x & 3u) == 0u);

    for (;;) {
        if (tid == 0) {
            int kind = 3; unsigned p0 = 0, p1 = 0;
            auto tryScan = [&]() -> bool {
                if (scan_done) return false;
                unsigned it = aadd(&ctl->scan_ticket, 1u);
                if (it >= SCAN_ITEMS) { scan_done = true; return false; }
                kind = 0; p0 = it; return true;
            };
            auto tryGemm = [&]() -> bool {
                for (unsigned s = 0; s < NSLICE; ++s) {
                    if (drmask & (1u << s)) continue;
                    if (aldu(&ctl->slice_cnt[s]) >= ROWS_PER_SLICE) {
                        unsigned t = aadd(&ctl->gemm_ticket[s], 1u);
                        if (t < GEMM_X) { kind = 1; p0 = s; p1 = t; return true; }
                        drmask |= (1u << s);
                    }
                }
                return false;
            };
            bool got = prefer_gemm ? (tryGemm() || tryScan())
                                   : (tryScan() || tryGemm());
            if (!got && drmask == 0xFFu) kind = 2;
            s_kind = kind; s_p0 = p0; s_p1 = p1;
        }
        __syncthreads();
        const int kind = s_kind;
        const unsigned p0 = s_p0, p1 = s_p1;

        if (kind == 2) break;

        if (kind == 0) {
            // ---------------- scan item: batch row b, ctx pair j ----------
            const unsigned b = p0 / 5u, j = p0 - b * 5u;
            const uintx4* src = reinterpret_cast<const uintx4*>(batch)
                              + (size_t)(b * CTX + 2 * j) * (VOCAB / 4);
            int* idxp = ctl->idx + b * CTX + 2 * j;

            auto chk = [&](uintx4 v, int u) {
                if ((v[0] | v[1] | v[2] | v[3]) != 0u) {
                    int e = u * 4;
                    if (!v[0]) e += v[1] ? 1 : (v[2] ? 2 : 3);
                    int c = (e >= VOCAB) ? 1 : 0;
                    asti(idxp + c, e - c * VOCAB);
                }
            };
            for (int u = tid; u + 768 < 16000; u += 1024) {   // 4 loads in flight
                uintx4 a0 = __builtin_nontemporal_load(src + u);
                uintx4 a1 = __builtin_nontemporal_load(src + u + 256);
                uintx4 a2 = __builtin_nontemporal_load(src + u + 512);
                uintx4 a3 = __builtin_nontemporal_load(src + u + 768);
                chk(a0, u); chk(a1, u + 256); chk(a2, u + 512); chk(a3, u + 768);
            }
            for (int u = tid + 15360; u < 16000; u += 256)
                chk(__builtin_nontemporal_load(src + u), u);

            __syncthreads();   // drains this block's atomic idx stores (vmcnt)
            if (tid == 0) {
                unsigned old = aadd(&ctl->row_cnt[b], 2u);
                s_flag = (old == CTX - 2);    // we are the row's completer
            }
            __syncthreads();
            if (s_flag) {
                if (tid < CTX) {
                    int v;
                    do { v = aldi(&ctl->idx[b * CTX + tid]); } while (v < 0);
                    s_idx[tid] = v;
                }
                __syncthreads();
                if (tid < DIM) {
                    float s = 0.f;
#pragma unroll
                    for (int c = 0; c < CTX; ++c) s += emb[s_idx[c] * DIM + tid];
                    s *= (1.f / CTX);
                    unsigned short hh = bf16_hi(s);
                    s_h[tid] = hh;
                    s_l[tid] = bf16_hi(s - bf16_back(hh));
                }
                __syncthreads();
                if (tid < 16) {
                    u4s8 vh, vl;
#pragma unroll
                    for (int q = 0; q < 8; ++q) { vh.s[q] = s_h[tid*8+q]; vl.s[q] = s_l[tid*8+q]; }
                    const int pos = ((int)b >> 4) * 256 + tid * 16 + ((int)b & 15);
                    unsigned long long* ph = reinterpret_cast<unsigned long long*>(&ash[pos]);
                    unsigned long long* pl = reinterpret_cast<unsigned long long*>(&asl[pos]);
                    astq(ph,     vh.q[0]); astq(ph + 1, vh.q[1]);
                    astq(pl,     vl.q[0]); astq(pl + 1, vl.q[1]);
                }
                __syncthreads();  // drain avg atomic stores before counting
                if (tid == 0) aadd(&ctl->slice_cnt[b >> 7], 1u);
            }
        } else if (kind == 1) {
            // ---------------- gemm tile (slice p0, col-tile p1): r7 body --
            const int wv   = tid >> 6;
            const int lane = tid & 63;
            const int l15  = lane & 15;
            const int kg   = lane >> 4;
            const int m_b0 = (int)p0 * 128 + wv * 16;
            const int n0   = (int)p1 * 64;

            f32x4 acc[2][4] = {};
#pragma unroll
            for (int k0i = 0; k0i < 4; ++k0i) {
                bf16x8 a_h[2], a_l[2];
#pragma unroll
                for (int mt = 0; mt < 2; ++mt) {
                    const int ai = ((m_b0 + mt * 64) >> 4) * 256 + k0i * 64 + lane;
                    a_h[mt] = *reinterpret_cast<const bf16x8*>(ash + ai);
                    a_l[mt] = *reinterpret_cast<const bf16x8*>(asl + ai);
                }
#pragma unroll
                for (int nt = 0; nt < 4; ++nt) {
                    const int bi = ((n0 >> 4) + nt) * 256 + k0i * 64 + lane;
                    bf16x8 b_h = *reinterpret_cast<const bf16x8*>(wsh + bi);
                    bf16x8 b_l = *reinterpret_cast<const bf16x8*>(wsl + bi);
#pragma unroll
                    for (int mt = 0; mt < 2; ++mt) {
                        acc[mt][nt] = __builtin_amdgcn_mfma_f32_16x16x32_bf16(a_h[mt], b_h, acc[mt][nt], 0, 0, 0);
                        acc[mt][nt] = __builtin_amdgcn_mfma_f32_16x16x32_bf16(a_h[mt], b_l, acc[mt][nt], 0, 0, 0);
                        acc[mt][nt] = __builtin_amdgcn_mfma_f32_16x16x32_bf16(a_l[mt], b_h, acc[mt][nt], 0, 0, 0);
                    }
                }
            }
#pragma unroll
            for (int mt = 0; mt < 2; ++mt) {
                float rs[4] = {0.f, 0.f, 0.f, 0.f};
#pragma unroll
                for (int nt = 0; nt < 4; ++nt) {
                    const int col = n0 + nt * 16 + l15;
#pragma unroll
                    for (int r = 0; r < 4; ++r) {
                        const int row = m_b0 + mt * 64 + kg * 4 + r;
                        float e = __expf(acc[mt][nt][r] - SHIFT);
                        out[(long long)row * VOCAB + col] = e;
                        rs[r] += e;
                    }
                }
#pragma unroll
                for (int r = 0; r < 4; ++r) {
#pragma unroll
                    for (int dd = 1; dd < 16; dd <<= 1)
                        rs[r] += __shfl_xor(rs[r], dd, 64);
                    if (l15 == 0)
                        atomicAdd(&ctl->psum[m_b0 + mt * 64 + kg * 4 + r], rs[r]);
                }
            }
        } else {
            if (tid == 0) __builtin_amdgcn_s_sleep(16);
        }
        __syncthreads();
    }
}

// ---------------------------------------------------------------------------
// finalize: scale row by 1/psum[row]. Separate kernel (dispatch boundary
// flushes gemm's plain out stores across XCDs).
// ---------------------------------------------------------------------------
__global__ __launch_bounds__(512) void finalize_kernel(
    const float* __restrict__ psum, float* __restrict__ out) {
    const float inv = 1.f / psum[blockIdx.x];
    float4* p = reinterpret_cast<float4*>(out + (long long)blockIdx.x * VOCAB);
    for (int k = threadIdx.x; k < VOCAB / 4; k += 512) {
        float4 v = p[k];
        v.x *= inv; v.y *= inv; v.z *= inv; v.w *= inv;
        p[k] = v;
    }
}

// ---------------------------------------------------------------------------
extern "C" void kernel_launch(void* const* d_in, const int* in_sizes, int n_in,
                              void* d_out, int out_size, void* d_ws, size_t ws_size,
                              hipStream_t stream) {
    const float* batch = (const float*)d_in[0];
    const float* emb   = (const float*)d_in[1];
    const float* w_out = (const float*)d_in[2];
    float*       out   = (float*)d_out;

    char* ws = (char*)d_ws;
    Ctl* ctl = (Ctl*)ws;
    ws += (sizeof(Ctl) + 255) & ~(size_t)255;
    uint4* ash = (uint4*)ws; ws += (size_t)(BATCH / 16) * 256 * 16;   // 256 KB
    uint4* asl = (uint4*)ws; ws += (size_t)(BATCH / 16) * 256 * 16;   // 256 KB
    uint4* wsh = (uint4*)ws; ws += (size_t)(VOCAB / 16) * 256 * 16;   // 8 MB
    uint4* wsl = (uint4*)ws;                                          // 8 MB

    init_kernel<<<40, 256, 0, stream>>>(ctl);
    convert_w_kernel<<<dim3(VOCAB / 256, 4), 256, 0, stream>>>(w_out, wsh, wsl);
    mega_kernel<<<MEGA_BLOCKS, 256, 0, stream>>>(batch, emb, ash, asl, wsh, wsl, out, ctl);
    finalize_kernel<<<BATCH, 512, 0, stream>>>(&ctl->psum[0], out);
}